// Round 4
// baseline (667.889 us; speedup 1.0000x reference)
//
#include <hip/hip_runtime.h>

#define TT 512
#define DD 64
#define BB 1024
#define PF 8               // prefetch depth (steps) in the recurrence
#define HH 8

__device__ __forceinline__ float fexp2(float x){ return __builtin_amdgcn_exp2f(x); }
__device__ __forceinline__ float frcp (float x){ return __builtin_amdgcn_rcpf(x); }

// DPP: quad_perm uniform selectors (direction-proof) and row_ror:4k whose
// direction is resolved by a runtime probe.
template<int C>
__device__ __forceinline__ float dppf(float x){
  return __int_as_float(__builtin_amdgcn_update_dpp(0, __float_as_int(x), C, 0xF, 0xF, true));
}
template<int C>
__device__ __forceinline__ int dppi(int x){
  return __builtin_amdgcn_update_dpp(0, x, C, 0xF, 0xF, true);
}

// lane^16 exchange within each 32-lane group (BitMode: and=0x1F, or=0, xor=0x10)
__device__ __forceinline__ float swz16(float x){
  return __int_as_float(__builtin_amdgcn_ds_swizzle(__float_as_int(x), 0x401F));
}

template<int N> struct IC { static constexpr int v = N; };

// ============================================================
// Kernel 1 (v4): layer-0 input projection, TRANSPOSED (lane = row).
// P[ph][e][t][32], slot pos for gate-row r: pos(r) = (gate*4+(j&3))*2+(j>>2).
// Inverse map used here: for slot p, r(p) = (p>>3)*8 + (p&1)*4 + ((p>>1)&3).
// 2048 blocks x 256 threads, 4 waves/block, wave owns 64 rows, lane r = row.
//  - x row lives in 64 VGPRs (16 direct global float4 loads; no LDS at all)
//  - W rows / biases are wave-uniform -> all-lane-same-address L1 broadcast
//  - store: per-lane float4 of 4 consecutive pos slots (L2 write-merge)
// Arithmetic per output value identical to v2 (same a0..a3 k-split, same
// final (a0+a1)+(a2+a3), bias seeded into a0) -> bit-exact.
// ============================================================
__global__ __launch_bounds__(256) void proj_kernel(
    const float* __restrict__ x,
    const float* __restrict__ eWih0, const float* __restrict__ eBih, const float* __restrict__ eBhh,
    const float* __restrict__ dWih0, const float* __restrict__ dBih, const float* __restrict__ dBhh,
    float* __restrict__ P)
{
  const int tid  = threadIdx.x;
  const int w    = tid >> 6;
  const int lane = tid & 63;
  const int row  = (blockIdx.x * 4 + w) * 64 + lane;
  const int e = row >> 9, t = row & 511;

  // my x row -> registers (each 128B line is touched by exactly one lane)
  float xr[64];
  const float* xrow = x + (size_t)row * 64;
#pragma unroll
  for (int kq = 0; kq < 16; ++kq) {
    float4 xv = *(const float4*)(xrow + kq * 4);
    xr[kq*4+0] = xv.x; xr[kq*4+1] = xv.y; xr[kq*4+2] = xv.z; xr[kq*4+3] = xv.w;
  }

#pragma unroll
  for (int ph = 0; ph < 2; ++ph) {
    const float* W  = ph ? dWih0 : eWih0;
    const float* Bi = ph ? dBih  : eBih;   // layer-0 block = first 32 floats
    const float* Bh = ph ? dBhh  : eBhh;
    float* Prow = P + ((size_t)((ph << 10) + e) * TT + t) * 32;

#pragma unroll 1
    for (int pq = 0; pq < 8; ++pq) {
      float res[4];
#pragma unroll
      for (int sub = 0; sub < 4; ++sub) {
        const int p = pq * 4 + sub;                      // P slot (compile-time)
        const int r = (p >> 3) * 8 + (p & 1) * 4 + ((p >> 1) & 3);  // gate-row
        const float* Wr = W + r * 64;
        float a0 = Bi[r] + Bh[r], a1 = 0.f, a2 = 0.f, a3 = 0.f;
#pragma unroll
        for (int kq = 0; kq < 16; ++kq) {
          float4 wv = *(const float4*)(Wr + kq * 4);     // uniform -> L1 bcast
          a0 = fmaf(wv.x, xr[kq*4+0], a0);
          a1 = fmaf(wv.y, xr[kq*4+1], a1);
          a2 = fmaf(wv.z, xr[kq*4+2], a2);
          a3 = fmaf(wv.w, xr[kq*4+3], a3);
        }
        res[sub] = (a0 + a1) + (a2 + a3);
      }
      float4 st; st.x = res[0]; st.y = res[1]; st.z = res[2]; st.w = res[3];
      *(float4*)(Prow + pq * 4) = st;
    }
  }
}

// ============================================================
// Kernel 2 (v4): scalar-lane recurrence with SOURCE-INTERLEAVED layer chains.
// 256 blocks x 128 threads = 512 waves = 2 waves/CU.
// Same lane mapping as v3 (verified): 32 lanes/elem, unit v=idx>>2, gate
// g=idx&3; h-broadcast via ds_swizzle lane^16 + cndmask + row_ror:4k DPP.
// lstep3 fuses the three skewed per-layer steps phase-by-phase so the three
// independent dependency chains interleave (the v3 scheduler serialized
// them: 740 cyc/step at 67% SIMD issue-busy). Per-value arithmetic and each
// accumulator's FMA order are IDENTICAL to v3 -> bit-exact.
// ============================================================
__global__ __launch_bounds__(128) void recur_kernel(
    const float* __restrict__ P,
    const float* __restrict__ h0,    const float* __restrict__ c0,
    const float* __restrict__ eWihR, const float* __restrict__ eWhh,
    const float* __restrict__ eBih,  const float* __restrict__ eBhh,
    const float* __restrict__ dWihR, const float* __restrict__ dWhh,
    const float* __restrict__ dBih,  const float* __restrict__ dBhh,
    const float* __restrict__ linW,  const float* __restrict__ linB,
    float* __restrict__ out)
{
  const int tid = threadIdx.x;
  const int idx = tid & 31;          // within-elem lane
  const int v   = idx >> 2;          // unit 0..7
  const int g   = idx & 3;           // torch gate (i,f,g,o)
  const int b   = v & 3;             // rotation base (low-col index)
  const bool rB = (v >= 4);          // DPP row-1 lanes
  const int e   = blockIdx.x * 4 + (tid >> 5);

  const bool is_tanh = (g == 2);
  const float ns_act = is_tanh ? -2.885390082f : -1.44269504f;
  const float a_act  = is_tanh ? 2.0f : 1.0f;
  const float b_act  = is_tanh ? -1.0f : 0.0f;

  // runtime direction probe for row_ror:4 (wave-uniform d = 1 or 3)
  const int qidx = (tid >> 2) & 3;
  const int p4 = dppi<0x124>(qidx);
  const int d  = __builtin_amdgcn_readfirstlane((p4 - qidx) & 3);

  float H[3], cs[3], sd[3];
  float bd1 = 0.f, bd2 = 0.f;
  float WS[3][8], WB[2][8], Bss[2];

#pragma unroll
  for (int l = 0; l < 3; ++l) {
    H[l]  = h0[((size_t)l * BB + e) * HH + v];
    cs[l] = c0[((size_t)l * BB + e) * HH + v];
  }

  // broadcast h[0..7] of my elem into A[4] (low h's) / Bv[4] (high h's),
  // rotation order: A[k] = h[(b+d*k)&3], Bv[k] = h[4+((b+d*k)&3)]
  auto bcast = [&](float hn, float* A, float* Bv) {
    float Hsw = swz16(hn);             // other row's h at my within-row quad
    float Lo = rB ? Hsw : hn;
    float Hi = rB ? hn : Hsw;
    A[0]  = Lo; A[1]  = dppf<0x124>(Lo); A[2]  = dppf<0x128>(Lo); A[3]  = dppf<0x12C>(Lo);
    Bv[0] = Hi; Bv[1] = dppf<0x124>(Hi); Bv[2] = dppf<0x128>(Hi); Bv[3] = dppf<0x12C>(Hi);
  };

  auto load_phase = [&](const float* WihR, const float* Whh,
                        const float* Bih, const float* Bhh) {
#pragma unroll
    for (int l = 0; l < 3; ++l) {
      const int r0 = l * 32 + g * 8 + v;
#pragma unroll
      for (int k = 0; k < 4; ++k) {
        const int col = (b + d * k) & 3;
        WS[l][k]     = Whh[r0 * 8 + col];
        WS[l][4 + k] = Whh[r0 * 8 + 4 + col];
      }
    }
#pragma unroll
    for (int l = 0; l < 2; ++l) {
      const int r0 = l * 32 + g * 8 + v;
#pragma unroll
      for (int k = 0; k < 4; ++k) {
        const int col = (b + d * k) & 3;
        WB[l][k]     = WihR[r0 * 8 + col];
        WB[l][4 + k] = WihR[r0 * 8 + 4 + col];
      }
      Bss[l] = Bih[(l + 1) * 32 + g * 8 + v] + Bhh[(l + 1) * 32 + g * 8 + v];
    }
    // self-dots from current h (layer-0 bias lives inside P)
#pragma unroll
    for (int l = 0; l < 3; ++l) {
      float A[4], Bv[4];
      bcast(H[l], A, Bv);
      float acc = l ? Bss[l - 1] : 0.f;
#pragma unroll
      for (int k = 0; k < 4; ++k) {
        acc = fmaf(WS[l][k],     A[k],  acc);
        acc = fmaf(WS[l][4 + k], Bv[k], acc);
      }
      sd[l] = acc;
    }
  };

  // single-layer step (used in peel / drain only; identical arithmetic)
  auto lstep = [&](auto LC, float in) -> float {
    constexpr int l = decltype(LC)::v;
    float pre = in + sd[l];
    float ex  = fexp2(ns_act * pre);
    float rc  = frcp(1.f + ex);
    float act = fmaf(a_act, rc, b_act);
    float Gi = dppf<0x00>(act);
    float Gf = dppf<0x55>(act);
    float Gg = dppf<0xAA>(act);
    float Go = dppf<0xFF>(act);
    float cn = fmaf(Gf, cs[l], Gi * Gg);
    cs[l] = cn;
    float tx = fexp2(-2.885390082f * cn);
    float tr = frcp(1.f + tx);
    float th = fmaf(2.f, tr, -1.f);
    float hn = Go * th;
    H[l] = hn;
    float A[4], Bv[4];
    bcast(hn, A, Bv);
    float accS;
    if constexpr (l > 0) accS = Bss[l - 1]; else accS = 0.f;
#pragma unroll
    for (int k = 0; k < 4; ++k) {
      accS = fmaf(WS[l][k],     A[k],  accS);
      accS = fmaf(WS[l][4 + k], Bv[k], accS);
    }
    sd[l] = accS;
    float accB = 0.f;
    if constexpr (l < 2) {
#pragma unroll
      for (int k = 0; k < 4; ++k) {
        accB = fmaf(WB[l][k],     A[k],  accB);
        accB = fmaf(WB[l][4 + k], Bv[k], accB);
      }
    }
    return accB;
  };

  // fused step: layer0(t), layer1(t-1), layer2(t-2) interleaved phase-by-phase.
  // The three chains are data-independent (skew); interleaving hides each
  // chain's transcendental/DPP/swizzle latency under the others' issue.
  auto lstep3 = [&](float in0, float in1, float in2, float& nb1, float& nb2) {
    float pre0 = in0 + sd[0];
    float pre1 = in1 + sd[1];
    float pre2 = in2 + sd[2];
    float ex0 = fexp2(ns_act * pre0);
    float ex1 = fexp2(ns_act * pre1);
    float ex2 = fexp2(ns_act * pre2);
    float rc0 = frcp(1.f + ex0);
    float rc1 = frcp(1.f + ex1);
    float rc2 = frcp(1.f + ex2);
    float ac0 = fmaf(a_act, rc0, b_act);
    float ac1 = fmaf(a_act, rc1, b_act);
    float ac2 = fmaf(a_act, rc2, b_act);
    float Gi0 = dppf<0x00>(ac0), Gi1 = dppf<0x00>(ac1), Gi2 = dppf<0x00>(ac2);
    float Gf0 = dppf<0x55>(ac0), Gf1 = dppf<0x55>(ac1), Gf2 = dppf<0x55>(ac2);
    float Gg0 = dppf<0xAA>(ac0), Gg1 = dppf<0xAA>(ac1), Gg2 = dppf<0xAA>(ac2);
    float Go0 = dppf<0xFF>(ac0), Go1 = dppf<0xFF>(ac1), Go2 = dppf<0xFF>(ac2);
    float cn0 = fmaf(Gf0, cs[0], Gi0 * Gg0);
    float cn1 = fmaf(Gf1, cs[1], Gi1 * Gg1);
    float cn2 = fmaf(Gf2, cs[2], Gi2 * Gg2);
    cs[0] = cn0; cs[1] = cn1; cs[2] = cn2;
    float tx0 = fexp2(-2.885390082f * cn0);
    float tx1 = fexp2(-2.885390082f * cn1);
    float tx2 = fexp2(-2.885390082f * cn2);
    float tr0 = frcp(1.f + tx0);
    float tr1 = frcp(1.f + tx1);
    float tr2 = frcp(1.f + tx2);
    float th0 = fmaf(2.f, tr0, -1.f);
    float th1 = fmaf(2.f, tr1, -1.f);
    float th2 = fmaf(2.f, tr2, -1.f);
    float hn0 = Go0 * th0;
    float hn1 = Go1 * th1;
    float hn2 = Go2 * th2;
    H[0] = hn0; H[1] = hn1; H[2] = hn2;
    float sw0 = swz16(hn0);
    float sw1 = swz16(hn1);
    float sw2 = swz16(hn2);
    float Lo0 = rB ? sw0 : hn0, Hi0 = rB ? hn0 : sw0;
    float Lo1 = rB ? sw1 : hn1, Hi1 = rB ? hn1 : sw1;
    float Lo2 = rB ? sw2 : hn2, Hi2 = rB ? hn2 : sw2;
    float A0[4], B0[4], A1[4], B1[4], A2[4], B2[4];
    A0[0] = Lo0; A0[1] = dppf<0x124>(Lo0); A0[2] = dppf<0x128>(Lo0); A0[3] = dppf<0x12C>(Lo0);
    B0[0] = Hi0; B0[1] = dppf<0x124>(Hi0); B0[2] = dppf<0x128>(Hi0); B0[3] = dppf<0x12C>(Hi0);
    A1[0] = Lo1; A1[1] = dppf<0x124>(Lo1); A1[2] = dppf<0x128>(Lo1); A1[3] = dppf<0x12C>(Lo1);
    B1[0] = Hi1; B1[1] = dppf<0x124>(Hi1); B1[2] = dppf<0x128>(Hi1); B1[3] = dppf<0x12C>(Hi1);
    A2[0] = Lo2; A2[1] = dppf<0x124>(Lo2); A2[2] = dppf<0x128>(Lo2); A2[3] = dppf<0x12C>(Lo2);
    B2[0] = Hi2; B2[1] = dppf<0x124>(Hi2); B2[2] = dppf<0x128>(Hi2); B2[3] = dppf<0x12C>(Hi2);
    float s0 = 0.f, s1 = Bss[0], s2 = Bss[1];
    float u0 = 0.f, u1 = 0.f;
#pragma unroll
    for (int k = 0; k < 4; ++k) {
      s0 = fmaf(WS[0][k],     A0[k], s0);
      s0 = fmaf(WS[0][4 + k], B0[k], s0);
      s1 = fmaf(WS[1][k],     A1[k], s1);
      s1 = fmaf(WS[1][4 + k], B1[k], s1);
      s2 = fmaf(WS[2][k],     A2[k], s2);
      s2 = fmaf(WS[2][4 + k], B2[k], s2);
      u0 = fmaf(WB[0][k],     A0[k], u0);
      u0 = fmaf(WB[0][4 + k], B0[k], u0);
      u1 = fmaf(WB[1][k],     A1[k], u1);
      u1 = fmaf(WB[1][4 + k], B1[k], u1);
    }
    sd[0] = s0; sd[1] = s1; sd[2] = s2;
    nb1 = u0; nb2 = u1;
  };

#pragma unroll 1
  for (int ph = 0; ph < 2; ++ph) {
    if (ph == 0) load_phase(eWihR, eWhh, eBih, eBhh);
    else         load_phase(dWihR, dWhh, dBih, dBhh);

    const int pos = (g * 4 + b) * 2 + (v >> 2);
    const float* Pb = P + ((size_t)((ph << 10) + e) * TT) * 32 + pos;

    // fill prefetch pipeline with steps 0..PF-1
    float pf[PF];
#pragma unroll
    for (int k = 0; k < PF; ++k) pf[k] = Pb[k * 32];

    // peeled group t = 0..7 (skew startup), refill t = 8..15
#pragma unroll
    for (int k = 0; k < PF; ++k) {
      float cur = pf[k];
      pf[k] = Pb[(k + PF) * 32];
      float n1 = lstep(IC<0>{}, cur);
      float n2 = 0.f;
      if (k >= 1) n2 = lstep(IC<1>{}, bd1);
      if (k >= 2) (void)lstep(IC<2>{}, bd2);
      bd1 = n1; bd2 = n2;
    }

    // main loop t = 8..503 with unclamped prefetch of t+8..t+15
#pragma unroll 1
    for (int t = PF; t < TT - PF; t += PF) {
      const float* Pq = Pb + (size_t)(t + PF) * 32;
#pragma unroll
      for (int k = 0; k < PF; ++k) {
        float cur = pf[k];
        pf[k] = Pq[k * 32];
        float n1, n2;
        lstep3(cur, bd1, bd2, n1, n2);
        bd1 = n1; bd2 = n2;
      }
    }
    // final group t = 504..511 (no refill)
#pragma unroll
    for (int k = 0; k < PF; ++k) {
      float cur = pf[k];
      float n1, n2;
      lstep3(cur, bd1, bd2, n1, n2);
      bd1 = n1; bd2 = n2;
    }

    // drain skew: layer1 t=511, layer2 t=510, layer2 t=511
    float dd = lstep(IC<1>{}, bd1);
    (void)lstep(IC<2>{}, bd2);
    (void)lstep(IC<2>{}, dd);
  }

  // epilogue: linear on final decoder layer-2 h
  float lwA[4], lwB[4];
#pragma unroll
  for (int k = 0; k < 4; ++k) {
    const int col = (b + d * k) & 3;
    lwA[k] = linW[col];
    lwB[k] = linW[4 + col];
  }
  float A[4], Bv[4];
  bcast(H[2], A, Bv);
  float pred = linB[0];
#pragma unroll
  for (int k = 0; k < 4; ++k) {
    pred = fmaf(lwA[k], A[k],  pred);
    pred = fmaf(lwB[k], Bv[k], pred);
  }
  if (idx == 0) out[e] = pred;
}

// ============================================================
// Fallback (ws too small): round-1 verified single-kernel version.
// ============================================================
__global__ __launch_bounds__(64) void seq2seq_fallback(
    const float* __restrict__ x, const float* __restrict__ h0, const float* __restrict__ c0,
    const float* __restrict__ eWih0, const float* __restrict__ eWihR, const float* __restrict__ eWhh,
    const float* __restrict__ eBih,  const float* __restrict__ eBhh,
    const float* __restrict__ dWih0, const float* __restrict__ dWihR, const float* __restrict__ dWhh,
    const float* __restrict__ dBih,  const float* __restrict__ dBhh,
    const float* __restrict__ linW,  const float* __restrict__ linB, float* __restrict__ out)
{
  const int tid = threadIdx.x;
  const int g   = tid & 31;
  const int grp = tid & 32;
  const int jj  = g & 7;
  const int e   = blockIdx.x * 2 + (tid >> 5);
  const bool is_tanh = ((g >> 3) == 2);
  const float s_act = is_tanh ? 2.885390082f : 1.44269504f;
  const float a_act = is_tanh ? 2.0f : 1.0f;
  const float b_act = is_tanh ? -1.0f : 0.0f;
  float hrep[3][8]; float cc[3];
#pragma unroll
  for (int l = 0; l < 3; ++l) {
#pragma unroll
    for (int k = 0; k < 8; ++k) hrep[l][k] = h0[((size_t)l * BB + e) * HH + k];
    cc[l] = c0[((size_t)l * BB + e) * HH + jj];
  }
  for (int p = 0; p < 2; ++p) {
    const float* Wih0 = p ? dWih0 : eWih0;  const float* WihR = p ? dWihR : eWihR;
    const float* Whh  = p ? dWhh  : eWhh;   const float* Bih  = p ? dBih  : eBih;
    const float* Bhh  = p ? dBhh  : eBhh;
    float Wx[64];
#pragma unroll
    for (int k = 0; k < 64; k += 4) {
      float4 w = *(const float4*)(Wih0 + g * 64 + k);
      Wx[k] = w.x; Wx[k+1] = w.y; Wx[k+2] = w.z; Wx[k+3] = w.w;
    }
    float Wh[3][8], Wi[2][8], bias[3];
#pragma unroll
    for (int l = 0; l < 3; ++l) {
#pragma unroll
      for (int k = 0; k < 8; ++k) Wh[l][k] = Whh[(l*32+g)*8+k];
      bias[l] = Bih[l*32+g] + Bhh[l*32+g];
    }
#pragma unroll
    for (int l = 0; l < 2; ++l)
#pragma unroll
      for (int k = 0; k < 8; ++k) Wi[l][k] = WihR[(l*32+g)*8+k];
    const float* xrow = x + (size_t)e * TT * DD;
    for (int t = 0; t < TT; ++t) {
      float4 acc = make_float4(bias[0], 0.f, 0.f, 0.f);
#pragma unroll
      for (int kc = 0; kc < 16; ++kc) {
        float4 xv = *(const float4*)(xrow + kc * 4);
        acc.x = fmaf(Wx[kc*4+0], xv.x, acc.x); acc.y = fmaf(Wx[kc*4+1], xv.y, acc.y);
        acc.z = fmaf(Wx[kc*4+2], xv.z, acc.z); acc.w = fmaf(Wx[kc*4+3], xv.w, acc.w);
      }
      float pre = (acc.x + acc.y) + (acc.z + acc.w);
      { float r0=0.f,r1=0.f;
#pragma unroll
        for (int k = 0; k < 8; k += 2) { r0=fmaf(Wh[0][k],hrep[0][k],r0); r1=fmaf(Wh[0][k+1],hrep[0][k+1],r1); }
        pre += r0 + r1; }
#pragma unroll
      for (int l = 0; l < 3; ++l) {
        if (l > 0) {
          float r0 = bias[l], r1 = 0.f;
#pragma unroll
          for (int k = 0; k < 8; k += 2) {
            r0=fmaf(Wi[l-1][k],hrep[l-1][k],r0); r1=fmaf(Wi[l-1][k+1],hrep[l-1][k+1],r1);
            r0=fmaf(Wh[l][k],hrep[l][k],r0);     r1=fmaf(Wh[l][k+1],hrep[l][k+1],r1);
          }
          pre = r0 + r1;
        }
        float act = fmaf(a_act, frcp(1.0f + fexp2(-s_act * pre)), b_act);
        float iv = __shfl(act, grp + jj);
        float fv = __shfl(act, grp + 8 + jj);
        float gv = __shfl(act, grp + 16 + jj);
        float ov = __shfl(act, grp + 24 + jj);
        float cn = fmaf(fv, cc[l], iv * gv);
        cc[l] = cn;
        float th = fmaf(2.0f, frcp(1.0f + fexp2(-2.885390082f * cn)), -1.0f);
        float hn = ov * th;
#pragma unroll
        for (int k = 0; k < 8; ++k) hrep[l][k] = __shfl(hn, grp + k);
      }
      xrow += DD;
    }
  }
  float pred = linB[0];
#pragma unroll
  for (int k = 0; k < 8; ++k) pred = fmaf(linW[k], hrep[2][k], pred);
  if (g == 0) out[e] = pred;
}

extern "C" void kernel_launch(void* const* d_in, const int* in_sizes, int n_in,
                              void* d_out, int out_size, void* d_ws, size_t ws_size,
                              hipStream_t stream) {
  const float* x     = (const float*)d_in[0];
  const float* h0    = (const float*)d_in[1];
  const float* c0    = (const float*)d_in[2];
  const float* eWih0 = (const float*)d_in[3];
  const float* eWihR = (const float*)d_in[4];
  const float* eWhh  = (const float*)d_in[5];
  const float* eBih  = (const float*)d_in[6];
  const float* eBhh  = (const float*)d_in[7];
  const float* dWih0 = (const float*)d_in[8];
  const float* dWihR = (const float*)d_in[9];
  const float* dWhh  = (const float*)d_in[10];
  const float* dBih  = (const float*)d_in[11];
  const float* dBhh  = (const float*)d_in[12];
  const float* linW  = (const float*)d_in[13];
  const float* linB  = (const float*)d_in[14];
  float* out = (float*)d_out;

  const size_t P_BYTES = (size_t)2 * BB * TT * 32 * sizeof(float);  // 128 MiB
  if (ws_size >= P_BYTES) {
    float* P = (float*)d_ws;
    proj_kernel<<<2048, 256, 0, stream>>>(x, eWih0, eBih, eBhh, dWih0, dBih, dBhh, P);
    recur_kernel<<<BB / 4, 128, 0, stream>>>(P, h0, c0, eWihR, eWhh, eBih, eBhh,
                                             dWihR, dWhh, dBih, dBhh, linW, linB, out);
  } else {
    seq2seq_fallback<<<BB / 2, 64, 0, stream>>>(x, h0, c0, eWih0, eWihR, eWhh, eBih, eBhh,
                                                dWih0, dWihR, dWhh, dBih, dBhh, linW, linB, out);
  }
}

// Round 5
// 573.847 us; speedup vs baseline: 1.1639x; 1.1639x over previous
//
#include <hip/hip_runtime.h>

#define TT 512
#define DD 64
#define BB 1024
#define PF 8               // prefetch depth (steps) in the recurrence
#define HH 8

__device__ __forceinline__ float fexp2(float x){ return __builtin_amdgcn_exp2f(x); }
__device__ __forceinline__ float frcp (float x){ return __builtin_amdgcn_rcpf(x); }

// DPP: quad_perm uniform selectors (direction-proof) and row_ror:4k whose
// direction is resolved by a runtime probe.
template<int C>
__device__ __forceinline__ float dppf(float x){
  return __int_as_float(__builtin_amdgcn_update_dpp(0, __float_as_int(x), C, 0xF, 0xF, true));
}
template<int C>
__device__ __forceinline__ int dppi(int x){
  return __builtin_amdgcn_update_dpp(0, x, C, 0xF, 0xF, true);
}

// lane^16 exchange within each 32-lane group (BitMode: and=0x1F, or=0, xor=0x10)
__device__ __forceinline__ float swz16(float x){
  return __int_as_float(__builtin_amdgcn_ds_swizzle(__float_as_int(x), 0x401F));
}

template<int N> struct IC { static constexpr int v = N; };

// ============================================================
// Kernel 1 (v5): layer-0 input projection, LDS-broadcast staging (as v2)
// but with 2 OUTPUTS PER LANE -> each ds_read_b128 feeds 8 FMAs instead
// of 4, halving the LDS-pipe time that dominated v2 (32 waves x 1024
// reads x ~12cyc = 164us/CU -> 82us/CU).
// P[ph][e][t][32], slot map (verified): pos(r) = (gate*4+(j&3))*2+(j>>2);
// inverse: slot p -> r(p) = (p>>3)*8 + (p&1)*4 + ((p>>1)&3), and for the
// lane's slot pair {2m, 2m+1}: r_even = (m>>2)*8 + (m&3), r_odd = r_even+4.
// Lane roles (64 lanes): rsel = lane>>5 (row parity in chunk),
// j = lane&31, ph = j>>4, m = j&15 -> slots 2m,2m+1 of phase ph.
// Chunk = 2 rows; both row addresses hit the same bank = 2-way = free.
// Per-output FMA chains byte-identical to v2 -> bit-exact output.
// ============================================================
__global__ __launch_bounds__(256) void proj_kernel(
    const float* __restrict__ x,
    const float* __restrict__ eWih0, const float* __restrict__ eBih, const float* __restrict__ eBhh,
    const float* __restrict__ dWih0, const float* __restrict__ dBih, const float* __restrict__ dBhh,
    float* __restrict__ P)
{
  __shared__ __align__(16) float xs[4][2][16 * 64];   // [wave][buf][row*64+k] = 32 KiB
  const int tid  = threadIdx.x;
  const int w    = tid >> 6;
  const int lane = tid & 63;
  const int rsel = lane >> 5;        // which row of the 2-row chunk
  const int j    = lane & 31;
  const int ph   = j >> 4;
  const int m    = j & 15;           // slot pair {2m, 2m+1} of phase ph
  const int r_even = (m >> 2) * 8 + (m & 3);
  const int r_odd  = r_even + 4;

  const float* W  = ph ? dWih0 : eWih0;
  const float* Bi = ph ? dBih  : eBih;
  const float* Bh = ph ? dBhh  : eBhh;
  const float bA = Bi[r_even] + Bh[r_even];
  const float bB = Bi[r_odd]  + Bh[r_odd];

  float Wa[64], Wb[64];
#pragma unroll
  for (int k = 0; k < 16; ++k) {
    float4 wq = *(const float4*)(W + r_even * 64 + k * 4);
    Wa[k*4+0] = wq.x; Wa[k*4+1] = wq.y; Wa[k*4+2] = wq.z; Wa[k*4+3] = wq.w;
  }
#pragma unroll
  for (int k = 0; k < 16; ++k) {
    float4 wq = *(const float4*)(W + r_odd * 64 + k * 4);
    Wb[k*4+0] = wq.x; Wb[k*4+1] = wq.y; Wb[k*4+2] = wq.z; Wb[k*4+3] = wq.w;
  }

  const int base_row = (blockIdx.x * 4 + w) * 64;     // 8192 waves x 64 rows
  const float* xg = x + (size_t)base_row * 64;

  float4 st[4];
  // stage group 0 into buf 0
#pragma unroll
  for (int i = 0; i < 4; ++i) st[i] = *(const float4*)(xg + i * 256 + lane * 4);
#pragma unroll
  for (int i = 0; i < 4; ++i) *(float4*)&xs[w][0][i * 256 + lane * 4] = st[i];
  // issue loads for group 1
#pragma unroll
  for (int i = 0; i < 4; ++i) st[i] = *(const float4*)(xg + 1024 + i * 256 + lane * 4);

#pragma unroll 1
  for (int g = 0; g < 4; ++g) {
    const float* buf = &xs[w][g & 1][0];
#pragma unroll 2
    for (int ci = 0; ci < 8; ++ci) {
      const int rib = ci * 2 + rsel;                 // row in buffer
      const float* xr = buf + rib * 64;
      float a0A = bA, a1A = 0.f, a2A = 0.f, a3A = 0.f;
      float a0B = bB, a1B = 0.f, a2B = 0.f, a3B = 0.f;
#pragma unroll
      for (int kc = 0; kc < 16; ++kc) {
        float4 xv = *(const float4*)(xr + kc * 4);
        a0A = fmaf(Wa[kc*4+0], xv.x, a0A);
        a1A = fmaf(Wa[kc*4+1], xv.y, a1A);
        a2A = fmaf(Wa[kc*4+2], xv.z, a2A);
        a3A = fmaf(Wa[kc*4+3], xv.w, a3A);
        a0B = fmaf(Wb[kc*4+0], xv.x, a0B);
        a1B = fmaf(Wb[kc*4+1], xv.y, a1B);
        a2B = fmaf(Wb[kc*4+2], xv.z, a2B);
        a3B = fmaf(Wb[kc*4+3], xv.w, a3B);
      }
      const int row = base_row + g * 16 + rib;
      const int e = row >> 9, t = row & 511;
      float2 res; res.x = (a0A + a1A) + (a2A + a3A);
                  res.y = (a0B + a1B) + (a2B + a3B);
      *(float2*)(P + ((size_t)((ph << 10) + e) * TT + t) * 32 + 2 * m) = res;
    }
    if (g < 3) {
      // commit staged group g+1 (waits vmcnt for st automatically)
#pragma unroll
      for (int i = 0; i < 4; ++i) *(float4*)&xs[w][(g + 1) & 1][i * 256 + lane * 4] = st[i];
      if (g < 2) {
        // issue loads for group g+2
#pragma unroll
        for (int i = 0; i < 4; ++i)
          st[i] = *(const float4*)(xg + (size_t)(g + 2) * 1024 + i * 256 + lane * 4);
      }
    }
  }
}

// ============================================================
// Kernel 2 (v4 — UNCHANGED, measured 298us, absmax 0.0): scalar-lane
// recurrence with source-interleaved layer chains (lstep3).
// ============================================================
__global__ __launch_bounds__(128) void recur_kernel(
    const float* __restrict__ P,
    const float* __restrict__ h0,    const float* __restrict__ c0,
    const float* __restrict__ eWihR, const float* __restrict__ eWhh,
    const float* __restrict__ eBih,  const float* __restrict__ eBhh,
    const float* __restrict__ dWihR, const float* __restrict__ dWhh,
    const float* __restrict__ dBih,  const float* __restrict__ dBhh,
    const float* __restrict__ linW,  const float* __restrict__ linB,
    float* __restrict__ out)
{
  const int tid = threadIdx.x;
  const int idx = tid & 31;          // within-elem lane
  const int v   = idx >> 2;          // unit 0..7
  const int g   = idx & 3;           // torch gate (i,f,g,o)
  const int b   = v & 3;             // rotation base (low-col index)
  const bool rB = (v >= 4);          // DPP row-1 lanes
  const int e   = blockIdx.x * 4 + (tid >> 5);

  const bool is_tanh = (g == 2);
  const float ns_act = is_tanh ? -2.885390082f : -1.44269504f;
  const float a_act  = is_tanh ? 2.0f : 1.0f;
  const float b_act  = is_tanh ? -1.0f : 0.0f;

  // runtime direction probe for row_ror:4 (wave-uniform d = 1 or 3)
  const int qidx = (tid >> 2) & 3;
  const int p4 = dppi<0x124>(qidx);
  const int d  = __builtin_amdgcn_readfirstlane((p4 - qidx) & 3);

  float H[3], cs[3], sd[3];
  float bd1 = 0.f, bd2 = 0.f;
  float WS[3][8], WB[2][8], Bss[2];

#pragma unroll
  for (int l = 0; l < 3; ++l) {
    H[l]  = h0[((size_t)l * BB + e) * HH + v];
    cs[l] = c0[((size_t)l * BB + e) * HH + v];
  }

  // broadcast h[0..7] of my elem into A[4] (low h's) / Bv[4] (high h's),
  // rotation order: A[k] = h[(b+d*k)&3], Bv[k] = h[4+((b+d*k)&3)]
  auto bcast = [&](float hn, float* A, float* Bv) {
    float Hsw = swz16(hn);             // other row's h at my within-row quad
    float Lo = rB ? Hsw : hn;
    float Hi = rB ? hn : Hsw;
    A[0]  = Lo; A[1]  = dppf<0x124>(Lo); A[2]  = dppf<0x128>(Lo); A[3]  = dppf<0x12C>(Lo);
    Bv[0] = Hi; Bv[1] = dppf<0x124>(Hi); Bv[2] = dppf<0x128>(Hi); Bv[3] = dppf<0x12C>(Hi);
  };

  auto load_phase = [&](const float* WihR, const float* Whh,
                        const float* Bih, const float* Bhh) {
#pragma unroll
    for (int l = 0; l < 3; ++l) {
      const int r0 = l * 32 + g * 8 + v;
#pragma unroll
      for (int k = 0; k < 4; ++k) {
        const int col = (b + d * k) & 3;
        WS[l][k]     = Whh[r0 * 8 + col];
        WS[l][4 + k] = Whh[r0 * 8 + 4 + col];
      }
    }
#pragma unroll
    for (int l = 0; l < 2; ++l) {
      const int r0 = l * 32 + g * 8 + v;
#pragma unroll
      for (int k = 0; k < 4; ++k) {
        const int col = (b + d * k) & 3;
        WB[l][k]     = WihR[r0 * 8 + col];
        WB[l][4 + k] = WihR[r0 * 8 + 4 + col];
      }
      Bss[l] = Bih[(l + 1) * 32 + g * 8 + v] + Bhh[(l + 1) * 32 + g * 8 + v];
    }
    // self-dots from current h (layer-0 bias lives inside P)
#pragma unroll
    for (int l = 0; l < 3; ++l) {
      float A[4], Bv[4];
      bcast(H[l], A, Bv);
      float acc = l ? Bss[l - 1] : 0.f;
#pragma unroll
      for (int k = 0; k < 4; ++k) {
        acc = fmaf(WS[l][k],     A[k],  acc);
        acc = fmaf(WS[l][4 + k], Bv[k], acc);
      }
      sd[l] = acc;
    }
  };

  // single-layer step (used in peel / drain only; identical arithmetic)
  auto lstep = [&](auto LC, float in) -> float {
    constexpr int l = decltype(LC)::v;
    float pre = in + sd[l];
    float ex  = fexp2(ns_act * pre);
    float rc  = frcp(1.f + ex);
    float act = fmaf(a_act, rc, b_act);
    float Gi = dppf<0x00>(act);
    float Gf = dppf<0x55>(act);
    float Gg = dppf<0xAA>(act);
    float Go = dppf<0xFF>(act);
    float cn = fmaf(Gf, cs[l], Gi * Gg);
    cs[l] = cn;
    float tx = fexp2(-2.885390082f * cn);
    float tr = frcp(1.f + tx);
    float th = fmaf(2.f, tr, -1.f);
    float hn = Go * th;
    H[l] = hn;
    float A[4], Bv[4];
    bcast(hn, A, Bv);
    float accS;
    if constexpr (l > 0) accS = Bss[l - 1]; else accS = 0.f;
#pragma unroll
    for (int k = 0; k < 4; ++k) {
      accS = fmaf(WS[l][k],     A[k],  accS);
      accS = fmaf(WS[l][4 + k], Bv[k], accS);
    }
    sd[l] = accS;
    float accB = 0.f;
    if constexpr (l < 2) {
#pragma unroll
      for (int k = 0; k < 4; ++k) {
        accB = fmaf(WB[l][k],     A[k],  accB);
        accB = fmaf(WB[l][4 + k], Bv[k], accB);
      }
    }
    return accB;
  };

  // fused step: layer0(t), layer1(t-1), layer2(t-2) interleaved phase-by-phase.
  auto lstep3 = [&](float in0, float in1, float in2, float& nb1, float& nb2) {
    float pre0 = in0 + sd[0];
    float pre1 = in1 + sd[1];
    float pre2 = in2 + sd[2];
    float ex0 = fexp2(ns_act * pre0);
    float ex1 = fexp2(ns_act * pre1);
    float ex2 = fexp2(ns_act * pre2);
    float rc0 = frcp(1.f + ex0);
    float rc1 = frcp(1.f + ex1);
    float rc2 = frcp(1.f + ex2);
    float ac0 = fmaf(a_act, rc0, b_act);
    float ac1 = fmaf(a_act, rc1, b_act);
    float ac2 = fmaf(a_act, rc2, b_act);
    float Gi0 = dppf<0x00>(ac0), Gi1 = dppf<0x00>(ac1), Gi2 = dppf<0x00>(ac2);
    float Gf0 = dppf<0x55>(ac0), Gf1 = dppf<0x55>(ac1), Gf2 = dppf<0x55>(ac2);
    float Gg0 = dppf<0xAA>(ac0), Gg1 = dppf<0xAA>(ac1), Gg2 = dppf<0xAA>(ac2);
    float Go0 = dppf<0xFF>(ac0), Go1 = dppf<0xFF>(ac1), Go2 = dppf<0xFF>(ac2);
    float cn0 = fmaf(Gf0, cs[0], Gi0 * Gg0);
    float cn1 = fmaf(Gf1, cs[1], Gi1 * Gg1);
    float cn2 = fmaf(Gf2, cs[2], Gi2 * Gg2);
    cs[0] = cn0; cs[1] = cn1; cs[2] = cn2;
    float tx0 = fexp2(-2.885390082f * cn0);
    float tx1 = fexp2(-2.885390082f * cn1);
    float tx2 = fexp2(-2.885390082f * cn2);
    float tr0 = frcp(1.f + tx0);
    float tr1 = frcp(1.f + tx1);
    float tr2 = frcp(1.f + tx2);
    float th0 = fmaf(2.f, tr0, -1.f);
    float th1 = fmaf(2.f, tr1, -1.f);
    float th2 = fmaf(2.f, tr2, -1.f);
    float hn0 = Go0 * th0;
    float hn1 = Go1 * th1;
    float hn2 = Go2 * th2;
    H[0] = hn0; H[1] = hn1; H[2] = hn2;
    float sw0 = swz16(hn0);
    float sw1 = swz16(hn1);
    float sw2 = swz16(hn2);
    float Lo0 = rB ? sw0 : hn0, Hi0 = rB ? hn0 : sw0;
    float Lo1 = rB ? sw1 : hn1, Hi1 = rB ? hn1 : sw1;
    float Lo2 = rB ? sw2 : hn2, Hi2 = rB ? hn2 : sw2;
    float A0[4], B0[4], A1[4], B1[4], A2[4], B2[4];
    A0[0] = Lo0; A0[1] = dppf<0x124>(Lo0); A0[2] = dppf<0x128>(Lo0); A0[3] = dppf<0x12C>(Lo0);
    B0[0] = Hi0; B0[1] = dppf<0x124>(Hi0); B0[2] = dppf<0x128>(Hi0); B0[3] = dppf<0x12C>(Hi0);
    A1[0] = Lo1; A1[1] = dppf<0x124>(Lo1); A1[2] = dppf<0x128>(Lo1); A1[3] = dppf<0x12C>(Lo1);
    B1[0] = Hi1; B1[1] = dppf<0x124>(Hi1); B1[2] = dppf<0x128>(Hi1); B1[3] = dppf<0x12C>(Hi1);
    A2[0] = Lo2; A2[1] = dppf<0x124>(Lo2); A2[2] = dppf<0x128>(Lo2); A2[3] = dppf<0x12C>(Lo2);
    B2[0] = Hi2; B2[1] = dppf<0x124>(Hi2); B2[2] = dppf<0x128>(Hi2); B2[3] = dppf<0x12C>(Hi2);
    float s0 = 0.f, s1 = Bss[0], s2 = Bss[1];
    float u0 = 0.f, u1 = 0.f;
#pragma unroll
    for (int k = 0; k < 4; ++k) {
      s0 = fmaf(WS[0][k],     A0[k], s0);
      s0 = fmaf(WS[0][4 + k], B0[k], s0);
      s1 = fmaf(WS[1][k],     A1[k], s1);
      s1 = fmaf(WS[1][4 + k], B1[k], s1);
      s2 = fmaf(WS[2][k],     A2[k], s2);
      s2 = fmaf(WS[2][4 + k], B2[k], s2);
      u0 = fmaf(WB[0][k],     A0[k], u0);
      u0 = fmaf(WB[0][4 + k], B0[k], u0);
      u1 = fmaf(WB[1][k],     A1[k], u1);
      u1 = fmaf(WB[1][4 + k], B1[k], u1);
    }
    sd[0] = s0; sd[1] = s1; sd[2] = s2;
    nb1 = u0; nb2 = u1;
  };

#pragma unroll 1
  for (int ph = 0; ph < 2; ++ph) {
    if (ph == 0) load_phase(eWihR, eWhh, eBih, eBhh);
    else         load_phase(dWihR, dWhh, dBih, dBhh);

    const int pos = (g * 4 + b) * 2 + (v >> 2);
    const float* Pb = P + ((size_t)((ph << 10) + e) * TT) * 32 + pos;

    // fill prefetch pipeline with steps 0..PF-1
    float pf[PF];
#pragma unroll
    for (int k = 0; k < PF; ++k) pf[k] = Pb[k * 32];

    // peeled group t = 0..7 (skew startup), refill t = 8..15
#pragma unroll
    for (int k = 0; k < PF; ++k) {
      float cur = pf[k];
      pf[k] = Pb[(k + PF) * 32];
      float n1 = lstep(IC<0>{}, cur);
      float n2 = 0.f;
      if (k >= 1) n2 = lstep(IC<1>{}, bd1);
      if (k >= 2) (void)lstep(IC<2>{}, bd2);
      bd1 = n1; bd2 = n2;
    }

    // main loop t = 8..503 with unclamped prefetch of t+8..t+15
#pragma unroll 1
    for (int t = PF; t < TT - PF; t += PF) {
      const float* Pq = Pb + (size_t)(t + PF) * 32;
#pragma unroll
      for (int k = 0; k < PF; ++k) {
        float cur = pf[k];
        pf[k] = Pq[k * 32];
        float n1, n2;
        lstep3(cur, bd1, bd2, n1, n2);
        bd1 = n1; bd2 = n2;
      }
    }
    // final group t = 504..511 (no refill)
#pragma unroll
    for (int k = 0; k < PF; ++k) {
      float cur = pf[k];
      float n1, n2;
      lstep3(cur, bd1, bd2, n1, n2);
      bd1 = n1; bd2 = n2;
    }

    // drain skew: layer1 t=511, layer2 t=510, layer2 t=511
    float dd = lstep(IC<1>{}, bd1);
    (void)lstep(IC<2>{}, bd2);
    (void)lstep(IC<2>{}, dd);
  }

  // epilogue: linear on final decoder layer-2 h
  float lwA[4], lwB[4];
#pragma unroll
  for (int k = 0; k < 4; ++k) {
    const int col = (b + d * k) & 3;
    lwA[k] = linW[col];
    lwB[k] = linW[4 + col];
  }
  float A[4], Bv[4];
  bcast(H[2], A, Bv);
  float pred = linB[0];
#pragma unroll
  for (int k = 0; k < 4; ++k) {
    pred = fmaf(lwA[k], A[k],  pred);
    pred = fmaf(lwB[k], Bv[k], pred);
  }
  if (idx == 0) out[e] = pred;
}

// ============================================================
// Fallback (ws too small): round-1 verified single-kernel version.
// ============================================================
__global__ __launch_bounds__(64) void seq2seq_fallback(
    const float* __restrict__ x, const float* __restrict__ h0, const float* __restrict__ c0,
    const float* __restrict__ eWih0, const float* __restrict__ eWihR, const float* __restrict__ eWhh,
    const float* __restrict__ eBih,  const float* __restrict__ eBhh,
    const float* __restrict__ dWih0, const float* __restrict__ dWihR, const float* __restrict__ dWhh,
    const float* __restrict__ dBih,  const float* __restrict__ dBhh,
    const float* __restrict__ linW,  const float* __restrict__ linB, float* __restrict__ out)
{
  const int tid = threadIdx.x;
  const int g   = tid & 31;
  const int grp = tid & 32;
  const int jj  = g & 7;
  const int e   = blockIdx.x * 2 + (tid >> 5);
  const bool is_tanh = ((g >> 3) == 2);
  const float s_act = is_tanh ? 2.885390082f : 1.44269504f;
  const float a_act = is_tanh ? 2.0f : 1.0f;
  const float b_act = is_tanh ? -1.0f : 0.0f;
  float hrep[3][8]; float cc[3];
#pragma unroll
  for (int l = 0; l < 3; ++l) {
#pragma unroll
    for (int k = 0; k < 8; ++k) hrep[l][k] = h0[((size_t)l * BB + e) * HH + k];
    cc[l] = c0[((size_t)l * BB + e) * HH + jj];
  }
  for (int p = 0; p < 2; ++p) {
    const float* Wih0 = p ? dWih0 : eWih0;  const float* WihR = p ? dWihR : eWihR;
    const float* Whh  = p ? dWhh  : eWhh;   const float* Bih  = p ? dBih  : eBih;
    const float* Bhh  = p ? dBhh  : eBhh;
    float Wx[64];
#pragma unroll
    for (int k = 0; k < 64; k += 4) {
      float4 w = *(const float4*)(Wih0 + g * 64 + k);
      Wx[k] = w.x; Wx[k+1] = w.y; Wx[k+2] = w.z; Wx[k+3] = w.w;
    }
    float Wh[3][8], Wi[2][8], bias[3];
#pragma unroll
    for (int l = 0; l < 3; ++l) {
#pragma unroll
      for (int k = 0; k < 8; ++k) Wh[l][k] = Whh[(l*32+g)*8+k];
      bias[l] = Bih[l*32+g] + Bhh[l*32+g];
    }
#pragma unroll
    for (int l = 0; l < 2; ++l)
#pragma unroll
      for (int k = 0; k < 8; ++k) Wi[l][k] = WihR[(l*32+g)*8+k];
    const float* xrow = x + (size_t)e * TT * DD;
    for (int t = 0; t < TT; ++t) {
      float4 acc = make_float4(bias[0], 0.f, 0.f, 0.f);
#pragma unroll
      for (int kc = 0; kc < 16; ++kc) {
        float4 xv = *(const float4*)(xrow + kc * 4);
        acc.x = fmaf(Wx[kc*4+0], xv.x, acc.x); acc.y = fmaf(Wx[kc*4+1], xv.y, acc.y);
        acc.z = fmaf(Wx[kc*4+2], xv.z, acc.z); acc.w = fmaf(Wx[kc*4+3], xv.w, acc.w);
      }
      float pre = (acc.x + acc.y) + (acc.z + acc.w);
      { float r0=0.f,r1=0.f;
#pragma unroll
        for (int k = 0; k < 8; k += 2) { r0=fmaf(Wh[0][k],hrep[0][k],r0); r1=fmaf(Wh[0][k+1],hrep[0][k+1],r1); }
        pre += r0 + r1; }
#pragma unroll
      for (int l = 0; l < 3; ++l) {
        if (l > 0) {
          float r0 = bias[l], r1 = 0.f;
#pragma unroll
          for (int k = 0; k < 8; k += 2) {
            r0=fmaf(Wi[l-1][k],hrep[l-1][k],r0); r1=fmaf(Wi[l-1][k+1],hrep[l-1][k+1],r1);
            r0=fmaf(Wh[l][k],hrep[l][k],r0);     r1=fmaf(Wh[l][k+1],hrep[l][k+1],r1);
          }
          pre = r0 + r1;
        }
        float act = fmaf(a_act, frcp(1.0f + fexp2(-s_act * pre)), b_act);
        float iv = __shfl(act, grp + jj);
        float fv = __shfl(act, grp + 8 + jj);
        float gv = __shfl(act, grp + 16 + jj);
        float ov = __shfl(act, grp + 24 + jj);
        float cn = fmaf(fv, cc[l], iv * gv);
        cc[l] = cn;
        float th = fmaf(2.0f, frcp(1.0f + fexp2(-2.885390082f * cn)), -1.0f);
        float hn = ov * th;
#pragma unroll
        for (int k = 0; k < 8; ++k) hrep[l][k] = __shfl(hn, grp + k);
      }
      xrow += DD;
    }
  }
  float pred = linB[0];
#pragma unroll
  for (int k = 0; k < 8; ++k) pred = fmaf(linW[k], hrep[2][k], pred);
  if (g == 0) out[e] = pred;
}

extern "C" void kernel_launch(void* const* d_in, const int* in_sizes, int n_in,
                              void* d_out, int out_size, void* d_ws, size_t ws_size,
                              hipStream_t stream) {
  const float* x     = (const float*)d_in[0];
  const float* h0    = (const float*)d_in[1];
  const float* c0    = (const float*)d_in[2];
  const float* eWih0 = (const float*)d_in[3];
  const float* eWihR = (const float*)d_in[4];
  const float* eWhh  = (const float*)d_in[5];
  const float* eBih  = (const float*)d_in[6];
  const float* eBhh  = (const float*)d_in[7];
  const float* dWih0 = (const float*)d_in[8];
  const float* dWihR = (const float*)d_in[9];
  const float* dWhh  = (const float*)d_in[10];
  const float* dBih  = (const float*)d_in[11];
  const float* dBhh  = (const float*)d_in[12];
  const float* linW  = (const float*)d_in[13];
  const float* linB  = (const float*)d_in[14];
  float* out = (float*)d_out;

  const size_t P_BYTES = (size_t)2 * BB * TT * 32 * sizeof(float);  // 128 MiB
  if (ws_size >= P_BYTES) {
    float* P = (float*)d_ws;
    proj_kernel<<<2048, 256, 0, stream>>>(x, eWih0, eBih, eBhh, dWih0, dBih, dBhh, P);
    recur_kernel<<<BB / 4, 128, 0, stream>>>(P, h0, c0, eWihR, eWhh, eBih, eBhh,
                                             dWihR, dWhh, dBih, dBhh, linW, linB, out);
  } else {
    seq2seq_fallback<<<BB / 2, 64, 0, stream>>>(x, h0, c0, eWih0, eWihR, eWhh, eBih, eBhh,
                                                dWih0, dWihR, dWhh, dBih, dBhh, linW, linB, out);
  }
}

// Round 6
// 520.977 us; speedup vs baseline: 1.2820x; 1.1015x over previous
//
#include <hip/hip_runtime.h>

#define TT 512
#define DD 64
#define BB 1024
#define PF 8               // prefetch depth (steps) in the recurrence
#define HH 8
#define WBLK 32            // P window (timesteps) held in LDS
#define NWIN (TT / WBLK)   // 16 windows per phase

__device__ __forceinline__ float fexp2(float x){ return __builtin_amdgcn_exp2f(x); }
__device__ __forceinline__ float frcp (float x){ return __builtin_amdgcn_rcpf(x); }

// DPP: quad_perm uniform selectors (direction-proof) and row_ror:4k whose
// direction is resolved by a runtime probe.
template<int C>
__device__ __forceinline__ float dppf(float x){
  return __int_as_float(__builtin_amdgcn_update_dpp(0, __float_as_int(x), C, 0xF, 0xF, true));
}
template<int C>
__device__ __forceinline__ int dppi(int x){
  return __builtin_amdgcn_update_dpp(0, x, C, 0xF, 0xF, true);
}

// lane^16 exchange within each 32-lane group (BitMode: and=0x1F, or=0, xor=0x10)
__device__ __forceinline__ float swz16(float x){
  return __int_as_float(__builtin_amdgcn_ds_swizzle(__float_as_int(x), 0x401F));
}

template<int N> struct IC { static constexpr int v = N; };

// ============================================================
// FUSED kernel: producer waves compute the layer-0 input projection into a
// double-buffered LDS window; consumer waves run the verified scalar-lane
// recurrence (v4 lstep3) reading P from LDS. P never touches global memory.
//
// 256 blocks x 256 threads (4 waves), 1 block/CU (96 KiB dynamic LDS):
//   waves 0-1 : consumers — exactly the v4 recur structure (bit-exact)
//   waves 2-3 : producers — 2 batch elems each, v5 projection math
//                (bit-exact P values: same slot map, same FMA chains)
// Window protocol (per phase): produce w=0; barrier; for w in 0..15:
//   {producers fill w+1 into buf[(w+1)&1] | consumers drain w from buf[w&1]};
//   barrier.  34 barriers total.
// LDS: Plds[2][WBLK][4][32] = 32 KiB | xst[4][WBLK*64] = 32 KiB (wave-private)
// ============================================================
__global__ __launch_bounds__(256) void fused_kernel(
    const float* __restrict__ x,
    const float* __restrict__ h0,    const float* __restrict__ c0,
    const float* __restrict__ eWih0, const float* __restrict__ eWihR, const float* __restrict__ eWhh,
    const float* __restrict__ eBih,  const float* __restrict__ eBhh,
    const float* __restrict__ dWih0, const float* __restrict__ dWihR, const float* __restrict__ dWhh,
    const float* __restrict__ dBih,  const float* __restrict__ dBhh,
    const float* __restrict__ linW,  const float* __restrict__ linB,
    float* __restrict__ out)
{
  extern __shared__ __align__(16) float smem[];
  float* Pbuf = smem;                       // [2][WBLK][4][32] = 8192 floats
  float* xst  = smem + 2 * WBLK * 4 * 32;   // [4][WBLK*64]     = 8192 floats

  const int tid  = threadIdx.x;
  const int wv   = tid >> 6;
  const int lane = tid & 63;
  const bool prod = (wv >= 2);

  // ---------------- consumer lane mapping (waves 0-1) ----------------
  const int idx = tid & 31;          // within-elem lane
  const int v   = idx >> 2;          // unit 0..7
  const int g   = idx & 3;           // torch gate (i,f,g,o)
  const int b   = v & 3;             // rotation base (low-col index)
  const bool rB = (v >= 4);          // DPP row-1 lanes
  const int erow = tid >> 5;         // 0..3 for consumers
  const int e    = blockIdx.x * 4 + erow;

  const bool is_tanh = (g == 2);
  const float ns_act = is_tanh ? -2.885390082f : -1.44269504f;
  const float a_act  = is_tanh ? 2.0f : 1.0f;
  const float b_act  = is_tanh ? -1.0f : 0.0f;

  // runtime direction probe for row_ror:4 (wave-uniform d = 1 or 3)
  const int qidx = (tid >> 2) & 3;
  const int p4 = dppi<0x124>(qidx);
  const int d  = __builtin_amdgcn_readfirstlane((p4 - qidx) & 3);

  float H[3], cs[3], sd[3];
  float bd1 = 0.f, bd2 = 0.f;
  float WS[3][8], WBr[2][8], Bss[2];

  if (!prod) {
#pragma unroll
    for (int l = 0; l < 3; ++l) {
      H[l]  = h0[((size_t)l * BB + e) * HH + v];
      cs[l] = c0[((size_t)l * BB + e) * HH + v];
    }
  }

  // ---------------- producer lane mapping (waves 2-3) ----------------
  const int rsel = lane >> 4;        // row-in-chunk 0..3
  const int m    = lane & 15;        // slot pair {2m, 2m+1}
  const int r_even = (m >> 2) * 8 + (m & 3);
  const int r_odd  = r_even + 4;
  const int p0 = (wv - 2) * 2;       // first of my 2 elems
  float Wa[64], Wb[64];
  float bA = 0.f, bB = 0.f;

  // ---------------- consumer helpers (verbatim v4) ----------------
  auto bcast = [&](float hn, float* A, float* Bv) {
    float Hsw = swz16(hn);
    float Lo = rB ? Hsw : hn;
    float Hi = rB ? hn : Hsw;
    A[0]  = Lo; A[1]  = dppf<0x124>(Lo); A[2]  = dppf<0x128>(Lo); A[3]  = dppf<0x12C>(Lo);
    Bv[0] = Hi; Bv[1] = dppf<0x124>(Hi); Bv[2] = dppf<0x128>(Hi); Bv[3] = dppf<0x12C>(Hi);
  };

  auto load_phase = [&](const float* WihR, const float* Whh,
                        const float* Bih, const float* Bhh) {
#pragma unroll
    for (int l = 0; l < 3; ++l) {
      const int r0 = l * 32 + g * 8 + v;
#pragma unroll
      for (int k = 0; k < 4; ++k) {
        const int col = (b + d * k) & 3;
        WS[l][k]     = Whh[r0 * 8 + col];
        WS[l][4 + k] = Whh[r0 * 8 + 4 + col];
      }
    }
#pragma unroll
    for (int l = 0; l < 2; ++l) {
      const int r0 = l * 32 + g * 8 + v;
#pragma unroll
      for (int k = 0; k < 4; ++k) {
        const int col = (b + d * k) & 3;
        WBr[l][k]     = WihR[r0 * 8 + col];
        WBr[l][4 + k] = WihR[r0 * 8 + 4 + col];
      }
      Bss[l] = Bih[(l + 1) * 32 + g * 8 + v] + Bhh[(l + 1) * 32 + g * 8 + v];
    }
#pragma unroll
    for (int l = 0; l < 3; ++l) {
      float A[4], Bv[4];
      bcast(H[l], A, Bv);
      float acc = l ? Bss[l - 1] : 0.f;
#pragma unroll
      for (int k = 0; k < 4; ++k) {
        acc = fmaf(WS[l][k],     A[k],  acc);
        acc = fmaf(WS[l][4 + k], Bv[k], acc);
      }
      sd[l] = acc;
    }
  };

  auto lstep = [&](auto LC, float in) -> float {
    constexpr int l = decltype(LC)::v;
    float pre = in + sd[l];
    float ex  = fexp2(ns_act * pre);
    float rc  = frcp(1.f + ex);
    float act = fmaf(a_act, rc, b_act);
    float Gi = dppf<0x00>(act);
    float Gf = dppf<0x55>(act);
    float Gg = dppf<0xAA>(act);
    float Go = dppf<0xFF>(act);
    float cn = fmaf(Gf, cs[l], Gi * Gg);
    cs[l] = cn;
    float tx = fexp2(-2.885390082f * cn);
    float tr = frcp(1.f + tx);
    float th = fmaf(2.f, tr, -1.f);
    float hn = Go * th;
    H[l] = hn;
    float A[4], Bv[4];
    bcast(hn, A, Bv);
    float accS;
    if constexpr (l > 0) accS = Bss[l - 1]; else accS = 0.f;
#pragma unroll
    for (int k = 0; k < 4; ++k) {
      accS = fmaf(WS[l][k],     A[k],  accS);
      accS = fmaf(WS[l][4 + k], Bv[k], accS);
    }
    sd[l] = accS;
    float accB = 0.f;
    if constexpr (l < 2) {
#pragma unroll
      for (int k = 0; k < 4; ++k) {
        accB = fmaf(WBr[l][k],     A[k],  accB);
        accB = fmaf(WBr[l][4 + k], Bv[k], accB);
      }
    }
    return accB;
  };

  auto lstep3 = [&](float in0, float in1, float in2, float& nb1, float& nb2) {
    float pre0 = in0 + sd[0];
    float pre1 = in1 + sd[1];
    float pre2 = in2 + sd[2];
    float ex0 = fexp2(ns_act * pre0);
    float ex1 = fexp2(ns_act * pre1);
    float ex2 = fexp2(ns_act * pre2);
    float rc0 = frcp(1.f + ex0);
    float rc1 = frcp(1.f + ex1);
    float rc2 = frcp(1.f + ex2);
    float ac0 = fmaf(a_act, rc0, b_act);
    float ac1 = fmaf(a_act, rc1, b_act);
    float ac2 = fmaf(a_act, rc2, b_act);
    float Gi0 = dppf<0x00>(ac0), Gi1 = dppf<0x00>(ac1), Gi2 = dppf<0x00>(ac2);
    float Gf0 = dppf<0x55>(ac0), Gf1 = dppf<0x55>(ac1), Gf2 = dppf<0x55>(ac2);
    float Gg0 = dppf<0xAA>(ac0), Gg1 = dppf<0xAA>(ac1), Gg2 = dppf<0xAA>(ac2);
    float Go0 = dppf<0xFF>(ac0), Go1 = dppf<0xFF>(ac1), Go2 = dppf<0xFF>(ac2);
    float cn0 = fmaf(Gf0, cs[0], Gi0 * Gg0);
    float cn1 = fmaf(Gf1, cs[1], Gi1 * Gg1);
    float cn2 = fmaf(Gf2, cs[2], Gi2 * Gg2);
    cs[0] = cn0; cs[1] = cn1; cs[2] = cn2;
    float tx0 = fexp2(-2.885390082f * cn0);
    float tx1 = fexp2(-2.885390082f * cn1);
    float tx2 = fexp2(-2.885390082f * cn2);
    float tr0 = frcp(1.f + tx0);
    float tr1 = frcp(1.f + tx1);
    float tr2 = frcp(1.f + tx2);
    float th0 = fmaf(2.f, tr0, -1.f);
    float th1 = fmaf(2.f, tr1, -1.f);
    float th2 = fmaf(2.f, tr2, -1.f);
    float hn0 = Go0 * th0;
    float hn1 = Go1 * th1;
    float hn2 = Go2 * th2;
    H[0] = hn0; H[1] = hn1; H[2] = hn2;
    float sw0 = swz16(hn0);
    float sw1 = swz16(hn1);
    float sw2 = swz16(hn2);
    float Lo0 = rB ? sw0 : hn0, Hi0 = rB ? hn0 : sw0;
    float Lo1 = rB ? sw1 : hn1, Hi1 = rB ? hn1 : sw1;
    float Lo2 = rB ? sw2 : hn2, Hi2 = rB ? hn2 : sw2;
    float A0[4], B0[4], A1[4], B1[4], A2[4], B2[4];
    A0[0] = Lo0; A0[1] = dppf<0x124>(Lo0); A0[2] = dppf<0x128>(Lo0); A0[3] = dppf<0x12C>(Lo0);
    B0[0] = Hi0; B0[1] = dppf<0x124>(Hi0); B0[2] = dppf<0x128>(Hi0); B0[3] = dppf<0x12C>(Hi0);
    A1[0] = Lo1; A1[1] = dppf<0x124>(Lo1); A1[2] = dppf<0x128>(Lo1); A1[3] = dppf<0x12C>(Lo1);
    B1[0] = Hi1; B1[1] = dppf<0x124>(Hi1); B1[2] = dppf<0x128>(Hi1); B1[3] = dppf<0x12C>(Hi1);
    A2[0] = Lo2; A2[1] = dppf<0x124>(Lo2); A2[2] = dppf<0x128>(Lo2); A2[3] = dppf<0x12C>(Lo2);
    B2[0] = Hi2; B2[1] = dppf<0x124>(Hi2); B2[2] = dppf<0x128>(Hi2); B2[3] = dppf<0x12C>(Hi2);
    float s0 = 0.f, s1 = Bss[0], s2 = Bss[1];
    float u0 = 0.f, u1 = 0.f;
#pragma unroll
    for (int k = 0; k < 4; ++k) {
      s0 = fmaf(WS[0][k],     A0[k], s0);
      s0 = fmaf(WS[0][4 + k], B0[k], s0);
      s1 = fmaf(WS[1][k],     A1[k], s1);
      s1 = fmaf(WS[1][4 + k], B1[k], s1);
      s2 = fmaf(WS[2][k],     A2[k], s2);
      s2 = fmaf(WS[2][4 + k], B2[k], s2);
      u0 = fmaf(WBr[0][k],     A0[k], u0);
      u0 = fmaf(WBr[0][4 + k], B0[k], u0);
      u1 = fmaf(WBr[1][k],     A1[k], u1);
      u1 = fmaf(WBr[1][4 + k], B1[k], u1);
    }
    sd[0] = s0; sd[1] = s1; sd[2] = s2;
    nb1 = u0; nb2 = u1;
  };

  const int pos_c = (g * 4 + b) * 2 + (v >> 2);   // consumer P slot

  // consume one 32-step window from buf = w&1 (peel = phase-start skew buildup)
  auto consume = [&](int w) {
    const float* Pw = Pbuf + ((w & 1) * WBLK * 4 * 32) + erow * 32 + pos_c;
    float pf[PF];
#pragma unroll
    for (int k = 0; k < PF; ++k) pf[k] = Pw[k * 128];
    if (w == 0) {
      // peeled group tl=0..7 (skew startup), refill tl=8..15
#pragma unroll
      for (int k = 0; k < PF; ++k) {
        float cur = pf[k];
        pf[k] = Pw[(PF + k) * 128];
        float n1 = lstep(IC<0>{}, cur);
        float n2 = 0.f;
        if (k >= 1) n2 = lstep(IC<1>{}, bd1);
        if (k >= 2) (void)lstep(IC<2>{}, bd2);
        bd1 = n1; bd2 = n2;
      }
#pragma unroll 1
      for (int gi = 1; gi < 3; ++gi) {
#pragma unroll
        for (int j = 0; j < PF; ++j) {
          float cur = pf[j];
          pf[j] = Pw[((gi + 1) * PF + j) * 128];
          float n1, n2;
          lstep3(cur, bd1, bd2, n1, n2);
          bd1 = n1; bd2 = n2;
        }
      }
    } else {
#pragma unroll 1
      for (int gi = 0; gi < 3; ++gi) {
#pragma unroll
        for (int j = 0; j < PF; ++j) {
          float cur = pf[j];
          pf[j] = Pw[((gi + 1) * PF + j) * 128];
          float n1, n2;
          lstep3(cur, bd1, bd2, n1, n2);
          bd1 = n1; bd2 = n2;
        }
      }
    }
    // final group tl=24..31, no refill
#pragma unroll
    for (int j = 0; j < PF; ++j) {
      float cur = pf[j];
      float n1, n2;
      lstep3(cur, bd1, bd2, n1, n2);
      bd1 = n1; bd2 = n2;
    }
  };

  // ---------------- producer: fill one window into buf ----------------
  // v5 math, bit-exact: slot pair {2m,2m+1} <- gate rows r_even/r_odd,
  // a0 seeded with bias, a0..a3 k-split, (a0+a1)+(a2+a3).
  auto produce = [&](int w, int buf) {
#pragma unroll 1
    for (int es = 0; es < 2; ++es) {
      const int p  = p0 + es;
      const float* xg = x + ((size_t)(blockIdx.x * 4 + p) * TT + w * WBLK) * 64;
      float* xp = xst + p * (WBLK * 64);
      float4 sv[8];
#pragma unroll
      for (int i = 0; i < 8; ++i) sv[i] = *(const float4*)(xg + i * 256 + lane * 4);
#pragma unroll
      for (int i = 0; i < 8; ++i) *(float4*)(xp + i * 256 + lane * 4) = sv[i];
#pragma unroll 1
      for (int ci = 0; ci < 8; ++ci) {
        const int rib = ci * 4 + rsel;
        const float* xr = xp + rib * 64;
        float a0A = bA, a1A = 0.f, a2A = 0.f, a3A = 0.f;
        float a0B = bB, a1B = 0.f, a2B = 0.f, a3B = 0.f;
#pragma unroll
        for (int kc = 0; kc < 16; ++kc) {
          float4 xv = *(const float4*)(xr + kc * 4);
          a0A = fmaf(Wa[kc*4+0], xv.x, a0A);
          a1A = fmaf(Wa[kc*4+1], xv.y, a1A);
          a2A = fmaf(Wa[kc*4+2], xv.z, a2A);
          a3A = fmaf(Wa[kc*4+3], xv.w, a3A);
          a0B = fmaf(Wb[kc*4+0], xv.x, a0B);
          a1B = fmaf(Wb[kc*4+1], xv.y, a1B);
          a2B = fmaf(Wb[kc*4+2], xv.z, a2B);
          a3B = fmaf(Wb[kc*4+3], xv.w, a3B);
        }
        float2 res;
        res.x = (a0A + a1A) + (a2A + a3A);
        res.y = (a0B + a1B) + (a2B + a3B);
        *(float2*)(Pbuf + ((size_t)(buf * WBLK + rib) * 4 + p) * 32 + 2 * m) = res;
      }
    }
  };

  // ---------------- main: 2 phases x 16 windows ----------------
#pragma unroll 1
  for (int ph = 0; ph < 2; ++ph) {
    if (prod) {
      const float* W  = ph ? dWih0 : eWih0;
      const float* Bi = ph ? dBih  : eBih;
      const float* Bh = ph ? dBhh  : eBhh;
      bA = Bi[r_even] + Bh[r_even];
      bB = Bi[r_odd]  + Bh[r_odd];
#pragma unroll
      for (int k = 0; k < 16; ++k) {
        float4 wq = *(const float4*)(W + r_even * 64 + k * 4);
        Wa[k*4+0] = wq.x; Wa[k*4+1] = wq.y; Wa[k*4+2] = wq.z; Wa[k*4+3] = wq.w;
      }
#pragma unroll
      for (int k = 0; k < 16; ++k) {
        float4 wq = *(const float4*)(W + r_odd * 64 + k * 4);
        Wb[k*4+0] = wq.x; Wb[k*4+1] = wq.y; Wb[k*4+2] = wq.z; Wb[k*4+3] = wq.w;
      }
      produce(0, 0);
    } else {
      if (ph == 0) load_phase(eWihR, eWhh, eBih, eBhh);
      else         load_phase(dWihR, dWhh, dBih, dBhh);
    }
    __syncthreads();

#pragma unroll 1
    for (int w = 0; w < NWIN; ++w) {
      if (prod) {
        if (w < NWIN - 1) produce(w + 1, (w + 1) & 1);
      } else {
        consume(w);
      }
      __syncthreads();
    }

    if (!prod) {
      // drain skew: layer1 t=511, layer2 t=510, layer2 t=511
      float dd = lstep(IC<1>{}, bd1);
      (void)lstep(IC<2>{}, bd2);
      (void)lstep(IC<2>{}, dd);
    }
  }

  // epilogue: linear on final decoder layer-2 h (consumers only)
  if (!prod) {
    float lwA[4], lwB[4];
#pragma unroll
    for (int k = 0; k < 4; ++k) {
      const int col = (b + d * k) & 3;
      lwA[k] = linW[col];
      lwB[k] = linW[4 + col];
    }
    float A[4], Bv[4];
    bcast(H[2], A, Bv);
    float pred = linB[0];
#pragma unroll
    for (int k = 0; k < 4; ++k) {
      pred = fmaf(lwA[k], A[k],  pred);
      pred = fmaf(lwB[k], Bv[k], pred);
    }
    if (idx == 0) out[e] = pred;
  }
}

extern "C" void kernel_launch(void* const* d_in, const int* in_sizes, int n_in,
                              void* d_out, int out_size, void* d_ws, size_t ws_size,
                              hipStream_t stream) {
  const float* x     = (const float*)d_in[0];
  const float* h0    = (const float*)d_in[1];
  const float* c0    = (const float*)d_in[2];
  const float* eWih0 = (const float*)d_in[3];
  const float* eWihR = (const float*)d_in[4];
  const float* eWhh  = (const float*)d_in[5];
  const float* eBih  = (const float*)d_in[6];
  const float* eBhh  = (const float*)d_in[7];
  const float* dWih0 = (const float*)d_in[8];
  const float* dWihR = (const float*)d_in[9];
  const float* dWhh  = (const float*)d_in[10];
  const float* dBih  = (const float*)d_in[11];
  const float* dBhh  = (const float*)d_in[12];
  const float* linW  = (const float*)d_in[13];
  const float* linB  = (const float*)d_in[14];
  float* out = (float*)d_out;

  // 96 KiB dynamic LDS: 64 KiB used (P dbuf + x stage) + padding to force
  // 1 block/CU (prevents 2-block packing that would contend consumer SIMDs).
  fused_kernel<<<BB / 4, 256, 98304, stream>>>(
      x, h0, c0, eWih0, eWihR, eWhh, eBih, eBhh,
      dWih0, dWihR, dWhh, dBih, dBhh, linW, linB, out);
}